// Round 6
// baseline (226.041 us; speedup 1.0000x reference)
//
#include <hip/hip_runtime.h>

// Problem constants (from reference)
constexpr int B  = 8;
constexpr int T  = 256;
constexpr int U1 = 65;
constexpr int DK = 640;   // D_ENC == D_pred
constexpr int V  = 1024;

constexpr int M_ENC  = B * T;    // 2048
constexpr int M_PRED = B * U1;   // 520

constexpr int TM = 16;                              // rows per block tile
constexpr int NB_ENC  = M_ENC / TM;                 // 128
constexpr int NB_PRED = (M_PRED + TM - 1) / TM;     // 33
constexpr int COLSPLIT = 8;                         // 128 cols per block
constexpr int NCOL4 = (V / COLSPLIT) / 4;           // 32 float4 per col-part

typedef float f32x4 __attribute__((ext_vector_type(4)));

__device__ __forceinline__ void fma4(float a, const float4& wv, float4& c) {
    c.x = fmaf(a, wv.x, c.x);
    c.y = fmaf(a, wv.y, c.y);
    c.z = fmaf(a, wv.z, c.z);
    c.w = fmaf(a, wv.w, c.w);
}

// ---------------------------------------------------------------------------
// enc_proj = enc @ W[:640]; pred_proj = pred @ W[640:] + bias
// Grid: (NB_ENC + NB_PRED) * COLSPLIT = 1288 blocks, 256 threads (4 waves).
// Block: 16 rows x 128 cols. Thread: 2 rows x 1 float4 col (acc 8 VGPR).
// LDS 40KB -> 4 blocks/CU resident = 16 waves/CU = 4 waves/SIMD.
// unroll 4 -> 16 W-loads in flight/wave; 4x16=64/SIMD >> ~31 needed.
// ---------------------------------------------------------------------------
__global__ __launch_bounds__(256) void proj_kernel(
    const float* __restrict__ enc, const float* __restrict__ pred,
    const float* __restrict__ W, const float* __restrict__ bias,
    float* __restrict__ enc_proj, float* __restrict__ pred_proj)
{
    __shared__ float a_s[TM * DK];   // 40 KB

    const int tid      = threadIdx.x;
    const int rowblock = blockIdx.x >> 3;           // which 16-row tile
    const int colpart  = blockIdx.x & 7;            // which 128-col part

    const bool isEnc = (rowblock < NB_ENC);
    const float* A   = isEnc ? enc : pred;
    float* O         = isEnc ? enc_proj : pred_proj;
    const float* Wb  = isEnc ? W : (W + (size_t)DK * V);
    const int M      = isEnc ? M_ENC : M_PRED;
    const int row0   = (isEnc ? rowblock : (rowblock - NB_ENC)) * TM;

    // ---- stage A tile (16 rows x 640 f32) into LDS ----
    {
        const float4* Ag = reinterpret_cast<const float4*>(A + (size_t)row0 * DK);
        float4* As = reinterpret_cast<float4*>(a_s);
        const int nf4 = TM * DK / 4;                // 2560
        for (int i = tid; i < nf4; i += 256) {
            int r = i / (DK / 4);                   // row within tile
            float4 v = make_float4(0.f, 0.f, 0.f, 0.f);
            if (row0 + r < M) v = Ag[i];
            As[i] = v;
        }
    }
    __syncthreads();

    // tx = col float4 slot (0..31), rg = row group (0..7 -> 2 rows each)
    const int tx = tid & (NCOL4 - 1);
    const int rg = tid >> 5;                        // half-wave uniform

    float4 acc0 = make_float4(0.f, 0.f, 0.f, 0.f);
    float4 acc1 = make_float4(0.f, 0.f, 0.f, 0.f);

    const float4* W4 = reinterpret_cast<const float4*>(Wb)
                       + (size_t)colpart * NCOL4 + tx;   // column of W, stride V/4 per d

    #pragma unroll 4
    for (int d = 0; d < DK; d += 4) {
        float4 w0 = W4[(size_t)(d + 0) * (V / 4)];
        float4 w1 = W4[(size_t)(d + 1) * (V / 4)];
        float4 w2 = W4[(size_t)(d + 2) * (V / 4)];
        float4 w3 = W4[(size_t)(d + 3) * (V / 4)];
        {
            const float4 av = *reinterpret_cast<const float4*>(
                &a_s[(rg * 2 + 0) * DK + d]);       // half-wave-uniform broadcast
            fma4(av.x, w0, acc0);
            fma4(av.y, w1, acc0);
            fma4(av.z, w2, acc0);
            fma4(av.w, w3, acc0);
        }
        {
            const float4 av = *reinterpret_cast<const float4*>(
                &a_s[(rg * 2 + 1) * DK + d]);
            fma4(av.x, w0, acc1);
            fma4(av.y, w1, acc1);
            fma4(av.z, w2, acc1);
            fma4(av.w, w3, acc1);
        }
    }

    // ---- epilogue: (+bias for pred rows), float4 store ----
    float4 bv = make_float4(0.f, 0.f, 0.f, 0.f);
    if (!isEnc) bv = reinterpret_cast<const float4*>(bias)[colpart * NCOL4 + tx];

    #pragma unroll
    for (int r = 0; r < 2; ++r) {
        const int row = row0 + rg * 2 + r;
        if (row < M) {
            float4 o = r ? acc1 : acc0;
            o.x += bv.x; o.y += bv.y; o.z += bv.z; o.w += bv.w;
            reinterpret_cast<float4*>(O)[(size_t)row * (V / 4) + colpart * NCOL4 + tx] = o;
        }
    }
}

// ---------------------------------------------------------------------------
// out[b,t,u,v] = enc_proj[b,t,v] + pred_proj[b,u,v]   (bias already folded in)
// Grid: B*T = 2048 blocks, 256 threads; thread owns one float4 of V.
// 8 blocks/CU -> 32 waves/CU; write stream fully TLP-covered.
// ---------------------------------------------------------------------------
__global__ __launch_bounds__(256) void bcast_kernel(
    const float* __restrict__ enc_proj, const float* __restrict__ pred_proj,
    float* __restrict__ out)
{
    const int bt  = blockIdx.x;          // 0..2047
    const int b   = bt >> 8;             // T = 256
    const int tid = threadIdx.x;

    const f32x4* e4 = reinterpret_cast<const f32x4*>(enc_proj) + (size_t)bt * (V / 4);
    const f32x4* p4 = reinterpret_cast<const f32x4*>(pred_proj) + (size_t)b * U1 * (V / 4);
    f32x4* o4       = reinterpret_cast<f32x4*>(out) + (size_t)bt * U1 * (V / 4);

    const f32x4 e = e4[tid];

    #pragma unroll 4
    for (int u = 0; u < U1; ++u) {
        f32x4 p = p4[(size_t)u * (V / 4) + tid];
        f32x4 o = e + p;
        __builtin_nontemporal_store(o, &o4[(size_t)u * (V / 4) + tid]);
    }
}

extern "C" void kernel_launch(void* const* d_in, const int* in_sizes, int n_in,
                              void* d_out, int out_size, void* d_ws, size_t ws_size,
                              hipStream_t stream)
{
    const float* enc  = (const float*)d_in[0];   // (8,256,640)
    const float* pred = (const float*)d_in[1];   // (8,65,640)
    const float* W    = (const float*)d_in[2];   // (1280,1024)
    const float* bias = (const float*)d_in[3];   // (1024,)
    float* out = (float*)d_out;                  // (8,256,65,1024)

    float* enc_proj  = (float*)d_ws;                         // 2048*1024 f32 = 8 MiB
    float* pred_proj = enc_proj + (size_t)M_ENC * V;         // 520*1024  f32 = 2 MiB

    proj_kernel<<<(NB_ENC + NB_PRED) * COLSPLIT, 256, 0, stream>>>(
        enc, pred, W, bias, enc_proj, pred_proj);

    bcast_kernel<<<M_ENC, 256, 0, stream>>>(enc_proj, pred_proj, out);
}

// Round 7
// 177.497 us; speedup vs baseline: 1.2735x; 1.2735x over previous
//
#include <hip/hip_runtime.h>

// Problem constants (from reference)
constexpr int B  = 8;
constexpr int T  = 256;
constexpr int U1 = 65;
constexpr int DK = 640;   // D_ENC == D_pred
constexpr int V  = 1024;

constexpr int M_ENC  = B * T;    // 2048
constexpr int M_PRED = B * U1;   // 520

constexpr int TM = 16;                              // rows per block tile
constexpr int NB_ENC  = M_ENC / TM;                 // 128
constexpr int NB_PRED = (M_PRED + TM - 1) / TM;     // 33
constexpr int COLSPLIT = 4;                         // 256 cols per block
constexpr int NCOL4 = (V / COLSPLIT) / 4;           // 64 float4 per col-part

typedef float f32x4 __attribute__((ext_vector_type(4)));

__device__ __forceinline__ void fma4(float a, const float4& wv, float4& c) {
    c.x = fmaf(a, wv.x, c.x);
    c.y = fmaf(a, wv.y, c.y);
    c.z = fmaf(a, wv.z, c.z);
    c.w = fmaf(a, wv.w, c.w);
}

// ---------------------------------------------------------------------------
// enc_proj = enc @ W[:640]; pred_proj = pred @ W[640:] + bias
// Grid: (NB_ENC + NB_PRED) * COLSPLIT = 644 blocks, 256 threads (4 waves).
// Block: 16 rows x 256 cols. Thread: 4 rows x 1 float4 col (acc 16 VGPR).
// 2.5 blocks/CU -> 10 waves/CU = 2.5 waves/SIMD.
// unroll 4 -> 16 W-loads in flight/wave; 2.5 x 16 = 40 >= ~31 needed
// (rate 2.5 waves x 4 loads / 128 VALU-cyc = 0.078/cyc x ~400 cyc latency).
// ---------------------------------------------------------------------------
__global__ __launch_bounds__(256) void proj_kernel(
    const float* __restrict__ enc, const float* __restrict__ pred,
    const float* __restrict__ W, const float* __restrict__ bias,
    float* __restrict__ enc_proj, float* __restrict__ pred_proj)
{
    __shared__ float a_s[TM * DK];   // 40 KB

    const int tid      = threadIdx.x;
    const int rowblock = blockIdx.x >> 2;           // which 16-row tile
    const int colpart  = blockIdx.x & 3;            // which 256-col part

    const bool isEnc = (rowblock < NB_ENC);
    const float* A   = isEnc ? enc : pred;
    float* O         = isEnc ? enc_proj : pred_proj;
    const float* Wb  = isEnc ? W : (W + (size_t)DK * V);
    const int M      = isEnc ? M_ENC : M_PRED;
    const int row0   = (isEnc ? rowblock : (rowblock - NB_ENC)) * TM;

    // ---- stage A tile (16 rows x 640 f32) into LDS ----
    // 256 threads = 16 rows x 16 lanes; each lane loads 10 float4 of its row.
    {
        const int r  = tid >> 4;                    // row within tile
        const int c0 = tid & 15;                    // f4 lane within row
        const float4* Ag = reinterpret_cast<const float4*>(A + (size_t)row0 * DK);
        float4* As = reinterpret_cast<float4*>(a_s);
        const bool valid = (row0 + r < M);
        #pragma unroll
        for (int k = 0; k < DK / 4 / 16; ++k) {     // 10
            const int i = r * (DK / 4) + c0 + k * 16;
            float4 v = make_float4(0.f, 0.f, 0.f, 0.f);
            if (valid) v = Ag[i];
            As[i] = v;
        }
    }
    __syncthreads();

    // tx = col float4 slot (0..63), rg = row group (0..3 -> 4 rows each)
    const int tx = tid & (NCOL4 - 1);
    const int rg = tid >> 6;                        // wave-uniform

    float4 acc[4];
    #pragma unroll
    for (int r = 0; r < 4; ++r) acc[r] = make_float4(0.f, 0.f, 0.f, 0.f);

    const float4* W4 = reinterpret_cast<const float4*>(Wb)
                       + (size_t)colpart * NCOL4 + tx;   // column of W, stride V/4 per d

    #pragma unroll 4
    for (int d = 0; d < DK; d += 4) {
        float4 w0 = W4[(size_t)(d + 0) * (V / 4)];
        float4 w1 = W4[(size_t)(d + 1) * (V / 4)];
        float4 w2 = W4[(size_t)(d + 2) * (V / 4)];
        float4 w3 = W4[(size_t)(d + 3) * (V / 4)];
        #pragma unroll
        for (int r = 0; r < 4; ++r) {
            const float4 av = *reinterpret_cast<const float4*>(
                &a_s[(rg * 4 + r) * DK + d]);       // wave-uniform -> LDS broadcast
            fma4(av.x, w0, acc[r]);
            fma4(av.y, w1, acc[r]);
            fma4(av.z, w2, acc[r]);
            fma4(av.w, w3, acc[r]);
        }
    }

    // ---- epilogue: (+bias for pred rows), float4 store ----
    float4 bv = make_float4(0.f, 0.f, 0.f, 0.f);
    if (!isEnc) bv = reinterpret_cast<const float4*>(bias)[colpart * NCOL4 + tx];

    #pragma unroll
    for (int r = 0; r < 4; ++r) {
        const int row = row0 + rg * 4 + r;
        if (row < M) {
            float4 o = acc[r];
            o.x += bv.x; o.y += bv.y; o.z += bv.z; o.w += bv.w;
            reinterpret_cast<float4*>(O)[(size_t)row * (V / 4) + colpart * NCOL4 + tx] = o;
        }
    }
}

// ---------------------------------------------------------------------------
// out[b,t,u,v] = enc_proj[b,t,v] + pred_proj[b,u,v]   (bias already folded in)
// Grid: B*T = 2048 blocks, 256 threads; thread owns one float4 of V.
// 8 blocks/CU -> 32 waves/CU; write stream fully TLP-covered.
// ---------------------------------------------------------------------------
__global__ __launch_bounds__(256) void bcast_kernel(
    const float* __restrict__ enc_proj, const float* __restrict__ pred_proj,
    float* __restrict__ out)
{
    const int bt  = blockIdx.x;          // 0..2047
    const int b   = bt >> 8;             // T = 256
    const int tid = threadIdx.x;

    const f32x4* e4 = reinterpret_cast<const f32x4*>(enc_proj) + (size_t)bt * (V / 4);
    const f32x4* p4 = reinterpret_cast<const f32x4*>(pred_proj) + (size_t)b * U1 * (V / 4);
    f32x4* o4       = reinterpret_cast<f32x4*>(out) + (size_t)bt * U1 * (V / 4);

    const f32x4 e = e4[tid];

    #pragma unroll 4
    for (int u = 0; u < U1; ++u) {
        f32x4 p = p4[(size_t)u * (V / 4) + tid];
        f32x4 o = e + p;
        __builtin_nontemporal_store(o, &o4[(size_t)u * (V / 4) + tid]);
    }
}

extern "C" void kernel_launch(void* const* d_in, const int* in_sizes, int n_in,
                              void* d_out, int out_size, void* d_ws, size_t ws_size,
                              hipStream_t stream)
{
    const float* enc  = (const float*)d_in[0];   // (8,256,640)
    const float* pred = (const float*)d_in[1];   // (8,65,640)
    const float* W    = (const float*)d_in[2];   // (1280,1024)
    const float* bias = (const float*)d_in[3];   // (1024,)
    float* out = (float*)d_out;                  // (8,256,65,1024)

    float* enc_proj  = (float*)d_ws;                         // 2048*1024 f32 = 8 MiB
    float* pred_proj = enc_proj + (size_t)M_ENC * V;         // 520*1024  f32 = 2 MiB

    proj_kernel<<<(NB_ENC + NB_PRED) * COLSPLIT, 256, 0, stream>>>(
        enc, pred, W, bias, enc_proj, pred_proj);

    bcast_kernel<<<M_ENC, 256, 0, stream>>>(enc_proj, pred_proj, out);
}

// Round 8
// 173.349 us; speedup vs baseline: 1.3040x; 1.0239x over previous
//
#include <hip/hip_runtime.h>

// Problem constants (from reference)
constexpr int B  = 8;
constexpr int T  = 256;
constexpr int U1 = 65;
constexpr int DK = 640;   // D_ENC == D_pred
constexpr int V  = 1024;

constexpr int M_ENC  = B * T;    // 2048
constexpr int M_PRED = B * U1;   // 520

typedef float f32x4 __attribute__((ext_vector_type(4)));

__device__ __forceinline__ void fma4(float a, const float4& wv, float4& c) {
    c.x = fmaf(a, wv.x, c.x);
    c.y = fmaf(a, wv.y, c.y);
    c.z = fmaf(a, wv.z, c.z);
    c.w = fmaf(a, wv.w, c.w);
}

// ===========================================================================
// MAIN PATH: 16-rows/thread, K-split x2 proj + summing bcast.
// L1-BW model: block = 16 rows x 1024 cols, each wave owns a DISTINCT
// 256-col W slice -> per 4-k iter: 16KB unique L1 traffic / 512 VALU-cyc
// = 32 B/cyc per CU (under ~64 B/cyc L1). Previous configs re-read W per
// row-group -> 2-4x oversubscribed L1 (the real reason R5/R7 sat at 88us).
// ===========================================================================
constexpr int KS  = 2;            // K-split factor
constexpr int KH  = DK / KS;      // 320
constexpr int TM2 = 16;           // rows per tile
constexpr int NT_ENC  = M_ENC / TM2;                  // 128
constexpr int NT_PRED = (M_PRED + TM2 - 1) / TM2;     // 33

// Grid: (NT_ENC + NT_PRED) * KS = 322 blocks, 256 threads.
__global__ __launch_bounds__(256) void proj16_kernel(
    const float* __restrict__ enc, const float* __restrict__ pred,
    const float* __restrict__ W, const float* __restrict__ bias,
    float* __restrict__ enc_part, float* __restrict__ pred_part)
{
    __shared__ float a_s[TM2 * KH];   // 16 x 320 f32 = 20 KB

    const int tid    = threadIdx.x;
    const int ks     = blockIdx.x & 1;          // which K half
    const int tileid = blockIdx.x >> 1;

    const bool isEnc = (tileid < NT_ENC);
    const float* A   = isEnc ? enc : pred;
    const float* Wb  = isEnc ? W : (W + (size_t)DK * V);
    float* O         = isEnc ? (enc_part + (size_t)ks * M_ENC * V)
                             : (pred_part + (size_t)ks * M_PRED * V);
    const int M      = isEnc ? M_ENC : M_PRED;
    const int row0   = (isEnc ? tileid : (tileid - NT_ENC)) * TM2;
    const int k0     = ks * KH;

    // ---- stage A tile (16 rows x 320 k) into LDS ----
    // 256 threads = 16 rows x 16 lanes; each lane loads 5 float4 of its row.
    {
        const int r  = tid >> 4;
        const int c0 = tid & 15;
        const bool valid = (row0 + r < M);
        const float4* Ag = reinterpret_cast<const float4*>(
            A + (size_t)(row0 + r) * DK + k0);
        float4* As = reinterpret_cast<float4*>(a_s) + r * (KH / 4);
        #pragma unroll
        for (int k = 0; k < KH / 4 / 16; ++k) {   // 5
            const int c = c0 + k * 16;
            float4 v = make_float4(0.f, 0.f, 0.f, 0.f);
            if (valid) v = Ag[c];
            As[c] = v;
        }
    }
    __syncthreads();

    float4 acc[TM2];
    #pragma unroll
    for (int r = 0; r < TM2; ++r) acc[r] = make_float4(0.f, 0.f, 0.f, 0.f);

    // thread owns float4 col = tid (0..255): waves read disjoint W slices.
    const float4* W4 = reinterpret_cast<const float4*>(Wb)
                       + (size_t)k0 * (V / 4) + tid;

    #pragma unroll 2
    for (int d = 0; d < KH; d += 4) {
        float4 w0 = W4[(size_t)(d + 0) * (V / 4)];
        float4 w1 = W4[(size_t)(d + 1) * (V / 4)];
        float4 w2 = W4[(size_t)(d + 2) * (V / 4)];
        float4 w3 = W4[(size_t)(d + 3) * (V / 4)];
        #pragma unroll
        for (int r = 0; r < TM2; ++r) {
            const float4 av = *reinterpret_cast<const float4*>(
                &a_s[r * KH + d]);                // block-uniform -> broadcast
            fma4(av.x, w0, acc[r]);
            fma4(av.y, w1, acc[r]);
            fma4(av.z, w2, acc[r]);
            fma4(av.w, w3, acc[r]);
        }
    }

    // ---- epilogue: bias folded into pred half 0 only ----
    float4 bv = make_float4(0.f, 0.f, 0.f, 0.f);
    if (!isEnc && ks == 0) bv = reinterpret_cast<const float4*>(bias)[tid];

    #pragma unroll
    for (int r = 0; r < TM2; ++r) {
        const int row = row0 + r;
        if (row < M) {
            float4 o = acc[r];
            o.x += bv.x; o.y += bv.y; o.z += bv.z; o.w += bv.w;
            reinterpret_cast<float4*>(O)[(size_t)row * (V / 4) + tid] = o;
        }
    }
}

// out[b,t,u,v] = (enc_a+enc_b)[b,t,v] + (pred_a+pred_b)[b,u,v]
__global__ __launch_bounds__(256) void bcast2_kernel(
    const float* __restrict__ enc_part, const float* __restrict__ pred_part,
    float* __restrict__ out)
{
    const int bt  = blockIdx.x;          // 0..2047
    const int b   = bt >> 8;             // T = 256
    const int tid = threadIdx.x;

    const f32x4* ea = reinterpret_cast<const f32x4*>(enc_part) + (size_t)bt * (V / 4);
    const f32x4* eb = ea + (size_t)M_ENC * (V / 4);
    const f32x4* pa = reinterpret_cast<const f32x4*>(pred_part)
                      + (size_t)b * U1 * (V / 4);
    const f32x4* pb = pa + (size_t)M_PRED * (V / 4);
    f32x4* o4       = reinterpret_cast<f32x4*>(out) + (size_t)bt * U1 * (V / 4);

    const f32x4 e = ea[tid] + eb[tid];

    #pragma unroll 4
    for (int u = 0; u < U1; ++u) {
        f32x4 p = pa[(size_t)u * (V / 4) + tid] + pb[(size_t)u * (V / 4) + tid];
        f32x4 o = e + p;
        __builtin_nontemporal_store(o, &o4[(size_t)u * (V / 4) + tid]);
    }
}

// ===========================================================================
// FALLBACK PATH (ws too small): R5 config — proven 176 us.
// ===========================================================================
constexpr int TM = 16;
constexpr int NB_ENC  = M_ENC / TM;                 // 128
constexpr int NB_PRED = (M_PRED + TM - 1) / TM;     // 33
constexpr int COLSPLIT = 4;
constexpr int NCOL4 = (V / COLSPLIT) / 4;           // 64

__global__ __launch_bounds__(256) void proj_kernel_fb(
    const float* __restrict__ enc, const float* __restrict__ pred,
    const float* __restrict__ W, const float* __restrict__ bias,
    float* __restrict__ enc_proj, float* __restrict__ pred_proj)
{
    __shared__ float a_s[TM * DK];

    const int tid      = threadIdx.x;
    const int rowblock = blockIdx.x >> 2;
    const int colpart  = blockIdx.x & 3;

    const bool isEnc = (rowblock < NB_ENC);
    const float* A   = isEnc ? enc : pred;
    float* O         = isEnc ? enc_proj : pred_proj;
    const float* Wb  = isEnc ? W : (W + (size_t)DK * V);
    const int M      = isEnc ? M_ENC : M_PRED;
    const int row0   = (isEnc ? rowblock : (rowblock - NB_ENC)) * TM;

    {
        const int r  = tid >> 4;
        const int c0 = tid & 15;
        const float4* Ag = reinterpret_cast<const float4*>(A + (size_t)row0 * DK);
        float4* As = reinterpret_cast<float4*>(a_s);
        const bool valid = (row0 + r < M);
        #pragma unroll
        for (int k = 0; k < DK / 4 / 16; ++k) {
            const int i = r * (DK / 4) + c0 + k * 16;
            float4 v = make_float4(0.f, 0.f, 0.f, 0.f);
            if (valid) v = Ag[i];
            As[i] = v;
        }
    }
    __syncthreads();

    const int tx = tid & (NCOL4 - 1);
    const int rg = tid >> 6;

    float4 acc[4];
    #pragma unroll
    for (int r = 0; r < 4; ++r) acc[r] = make_float4(0.f, 0.f, 0.f, 0.f);

    const float4* W4 = reinterpret_cast<const float4*>(Wb)
                       + (size_t)colpart * NCOL4 + tx;

    #pragma unroll 2
    for (int d = 0; d < DK; d += 4) {
        float4 w0 = W4[(size_t)(d + 0) * (V / 4)];
        float4 w1 = W4[(size_t)(d + 1) * (V / 4)];
        float4 w2 = W4[(size_t)(d + 2) * (V / 4)];
        float4 w3 = W4[(size_t)(d + 3) * (V / 4)];
        #pragma unroll
        for (int r = 0; r < 4; ++r) {
            const float4 av = *reinterpret_cast<const float4*>(
                &a_s[(rg * 4 + r) * DK + d]);
            fma4(av.x, w0, acc[r]);
            fma4(av.y, w1, acc[r]);
            fma4(av.z, w2, acc[r]);
            fma4(av.w, w3, acc[r]);
        }
    }

    float4 bv = make_float4(0.f, 0.f, 0.f, 0.f);
    if (!isEnc) bv = reinterpret_cast<const float4*>(bias)[colpart * NCOL4 + tx];

    #pragma unroll
    for (int r = 0; r < 4; ++r) {
        const int row = row0 + rg * 4 + r;
        if (row < M) {
            float4 o = acc[r];
            o.x += bv.x; o.y += bv.y; o.z += bv.z; o.w += bv.w;
            reinterpret_cast<float4*>(O)[(size_t)row * (V / 4) + colpart * NCOL4 + tx] = o;
        }
    }
}

__global__ __launch_bounds__(256) void bcast_kernel_fb(
    const float* __restrict__ enc_proj, const float* __restrict__ pred_proj,
    float* __restrict__ out)
{
    const int bt  = blockIdx.x;
    const int b   = bt >> 8;
    const int tid = threadIdx.x;

    const f32x4* e4 = reinterpret_cast<const f32x4*>(enc_proj) + (size_t)bt * (V / 4);
    const f32x4* p4 = reinterpret_cast<const f32x4*>(pred_proj) + (size_t)b * U1 * (V / 4);
    f32x4* o4       = reinterpret_cast<f32x4*>(out) + (size_t)bt * U1 * (V / 4);

    const f32x4 e = e4[tid];

    #pragma unroll 4
    for (int u = 0; u < U1; ++u) {
        f32x4 p = p4[(size_t)u * (V / 4) + tid];
        f32x4 o = e + p;
        __builtin_nontemporal_store(o, &o4[(size_t)u * (V / 4) + tid]);
    }
}

extern "C" void kernel_launch(void* const* d_in, const int* in_sizes, int n_in,
                              void* d_out, int out_size, void* d_ws, size_t ws_size,
                              hipStream_t stream)
{
    const float* enc  = (const float*)d_in[0];   // (8,256,640)
    const float* pred = (const float*)d_in[1];   // (8,65,640)
    const float* W    = (const float*)d_in[2];   // (1280,1024)
    const float* bias = (const float*)d_in[3];   // (1024,)
    float* out = (float*)d_out;                  // (8,256,65,1024)

    const size_t need = (size_t)(KS * M_ENC + KS * M_PRED) * V * sizeof(float); // ~21 MB

    if (ws_size >= need) {
        float* enc_part  = (float*)d_ws;                             // 2 x 8 MiB
        float* pred_part = enc_part + (size_t)KS * M_ENC * V;        // 2 x 2.1 MiB

        proj16_kernel<<<(NT_ENC + NT_PRED) * KS, 256, 0, stream>>>(
            enc, pred, W, bias, enc_part, pred_part);
        bcast2_kernel<<<M_ENC, 256, 0, stream>>>(enc_part, pred_part, out);
    } else {
        float* enc_proj  = (float*)d_ws;
        float* pred_proj = enc_proj + (size_t)M_ENC * V;

        proj_kernel_fb<<<(NB_ENC + NB_PRED) * COLSPLIT, 256, 0, stream>>>(
            enc, pred, W, bias, enc_proj, pred_proj);
        bcast_kernel_fb<<<M_ENC, 256, 0, stream>>>(enc_proj, pred_proj, out);
    }
}